// Round 5
// baseline (251.639 us; speedup 1.0000x reference)
//
#include <hip/hip_runtime.h>

// DropNorm: B=4096 rows, F=8192 features, fp32.
//   n = F/2; mu = sum(x*m)/n; sigma2 = sum(((x-mu)*m)^2)/(n-1)
//   out = gamma*m*(x-mu)*rsqrt(sigma2^2 + 1e-4) + beta   [sigma2 SQUARED: quirk]
//
// R5: amortize broadcast traffic. R1-R4 all moved 160-192 KB of vmem per
// 32 KB row: the m01/mg/beta broadcasts (96 KB/row) dominated the per-CU
// vector-memory pipe (~16 B/cyc/CU observed) and thrashed the 32 KB L1.
// Fix: 4 rows/block (row per wave, held in registers), mg+beta staged in
// LDS once per block (LDS port is separate from vmem), mask packed to bytes.
// Per-row vmem: 32+2+16+32 = 82 KB vs 192.

constexpr int Bn = 4096;
constexpr int Fn = 8192;
constexpr int NT = 256;            // 4 waves per block
constexpr int RPB = 4;             // rows per block = waves per block
constexpr int IT = Fn / 4 / 64;    // 32 f4-iterations per lane per row

typedef float f4 __attribute__((ext_vector_type(4)));
typedef const __attribute__((address_space(1))) unsigned int* gp_t; // global
typedef __attribute__((address_space(3))) unsigned int* lp_t;       // LDS

#define EPSV 1e-4f

// Prep: detect mask storage layout (uint8 bool vs int32) and materialize
//   m01b[j] = mask ? 1 : 0   (uchar, 8 KB)
//   mg[j]   = mask ? gamma[j] : 0.0   (fp32, 32 KB)
// Detection: count nonzero among the first Fn BYTES. uint8 layout -> exactly
// Fn/2 = 4096; int32 layout -> those bytes span only 2048 ints -> count <= 2048.
__global__ __launch_bounds__(NT) void prep_kernel(const void* __restrict__ mask_raw,
                                                  const float* __restrict__ gamma,
                                                  unsigned char* __restrict__ m01b,
                                                  float* __restrict__ mg) {
    const unsigned char* mb = (const unsigned char*)mask_raw;
    const int* mi = (const int*)mask_raw;
    const int tid = threadIdx.x;

    int cnt = 0;
    for (int j = tid; j < Fn; j += NT) cnt += (mb[j] != 0) ? 1 : 0;
    for (int off = 32; off > 0; off >>= 1) cnt += __shfl_down(cnt, off, 64);

    __shared__ int wc[NT / 64];
    __shared__ int flag;
    if ((tid & 63) == 0) wc[tid >> 6] = cnt;
    __syncthreads();
    if (tid == 0) {
        int total = wc[0] + wc[1] + wc[2] + wc[3];
        flag = (total == Fn / 2) ? 1 : 0;   // 1 = uint8 layout, 0 = int32 layout
    }
    __syncthreads();
    const bool u8 = (flag != 0);

    const int per_block = Fn / gridDim.x;
    const int base = blockIdx.x * per_block;
    for (int j = base + tid; j < base + per_block; j += NT) {
        const bool on = u8 ? (mb[j] != 0) : (mi[j] != 0);
        m01b[j] = on ? 1 : 0;
        mg[j]   = on ? gamma[j] : 0.0f;
    }
}

__global__ __launch_bounds__(NT, 2) void dropnorm_kernel(const float* __restrict__ x,
                                                         const unsigned char* __restrict__ m01b,
                                                         const float* __restrict__ mg,
                                                         const float* __restrict__ beta,
                                                         float* __restrict__ out) {
    __shared__ f4 smg[Fn / 4];   // 32 KB
    __shared__ f4 sbt[Fn / 4];   // 32 KB

    const int tid  = threadIdx.x;
    const int wave = tid >> 6;
    const int lane = tid & 63;
    const int row  = blockIdx.x * RPB + wave;     // one row per wave

    // ---- 1) issue this wave's row loads first (32 dwordx4, all in flight)
    const f4* __restrict__ xr = (const f4*)(x + (size_t)row * Fn);
    f4 xv[IT];
#pragma unroll
    for (int k = 0; k < IT; ++k) xv[k] = xr[k * 64 + lane];

    // mask words: uchar4 per f4-group, as uint loads (coalesced, tiny: 2 KB/row)
    const unsigned int* __restrict__ mb = (const unsigned int*)m01b;
    unsigned int mw[IT];
#pragma unroll
    for (int k = 0; k < IT; ++k) mw[k] = mb[k * 64 + lane];

    // ---- 2) stage mg + beta into LDS once per block (DMA: no VGPR round-trip)
    {
        const char* g1 = (const char*)mg   + wave * 8192 + lane * 16;
        const char* g2 = (const char*)beta + wave * 8192 + lane * 16;
        char* l1 = (char*)smg + wave * 8192;   // wave-uniform base + lane*16
        char* l2 = (char*)sbt + wave * 8192;
#pragma unroll
        for (int i = 0; i < 8; ++i) {
            __builtin_amdgcn_global_load_lds((gp_t)(g1 + i * 1024), (lp_t)(l1 + i * 1024), 16, 0, 0);
            __builtin_amdgcn_global_load_lds((gp_t)(g2 + i * 1024), (lp_t)(l2 + i * 1024), 16, 0, 0);
        }
    }

    // ---- 3) stats (registers only, exact masked select)
    float s = 0.f, ss = 0.f;
#pragma unroll
    for (int k = 0; k < IT; ++k) {
        const unsigned int m = mw[k];
        const float a0 = (m & 0x000000ffu) ? xv[k].x : 0.f;
        const float a1 = (m & 0x0000ff00u) ? xv[k].y : 0.f;
        const float a2 = (m & 0x00ff0000u) ? xv[k].z : 0.f;
        const float a3 = (m & 0xff000000u) ? xv[k].w : 0.f;
        s  += (a0 + a1) + (a2 + a3);
        ss += (a0 * a0 + a1 * a1) + (a2 * a2 + a3 * a3);
    }
    for (int off = 32; off > 0; off >>= 1) {
        s  += __shfl_down(s, off, 64);
        ss += __shfl_down(ss, off, 64);
    }
    const float S  = __shfl(s, 0, 64);    // broadcast wave totals
    const float SS = __shfl(ss, 0, 64);

    const float n  = (float)(Fn / 2);
    const float mu = S / n;
    // sum(diff^2) = sum(x^2 m) - n*mu^2   (sum(m) == n exactly)
    const float sigma2 = (SS - n * mu * mu) / (n - 1.0f);
    const float inv = rsqrtf(sigma2 * sigma2 + EPSV);  // quirk: sigma2 squared

    __syncthreads();   // smg/sbt staged (barrier drains the DMA vmcnt)

    // ---- 4) epilogue: row from registers, scale/shift from LDS, stream out
    f4* __restrict__ o4 = (f4*)(out + (size_t)row * Fn);
#pragma unroll
    for (int k = 0; k < IT; ++k) {
        const int j = k * 64 + lane;
        const f4 g = smg[j];
        const f4 b = sbt[j];
        f4 o;
        o.x = g.x * (xv[k].x - mu) * inv + b.x;
        o.y = g.y * (xv[k].y - mu) * inv + b.y;
        o.z = g.z * (xv[k].z - mu) * inv + b.z;
        o.w = g.w * (xv[k].w - mu) * inv + b.w;
        __builtin_nontemporal_store(o, o4 + j);
    }
}

extern "C" void kernel_launch(void* const* d_in, const int* in_sizes, int n_in,
                              void* d_out, int out_size, void* d_ws, size_t ws_size,
                              hipStream_t stream) {
    const float* x     = (const float*)d_in[0];
    const float* gamma = (const float*)d_in[1];
    const float* beta  = (const float*)d_in[2];
    const void*  mask  = d_in[3];
    float* out = (float*)d_out;

    unsigned char* m01b = (unsigned char*)d_ws;      // 8 KB
    float* mg = (float*)((char*)d_ws + Fn);          // 32 KB, 16-B aligned

    prep_kernel<<<16, NT, 0, stream>>>(mask, gamma, m01b, mg);
    dropnorm_kernel<<<Bn / RPB, NT, 0, stream>>>(x, m01b, mg, beta, out);
}